// Round 3
// baseline (300.423 us; speedup 1.0000x reference)
//
#include <hip/hip_runtime.h>
#include <math.h>

#define N 10000
#define DIN 256
#define DOUT 128
#define CAP 192
#define MAXP 400000
#define LBUF 2048
#define C0 1.6487212707001282f   // exp(sigmoid(0)) = exp(0.5)

// ---------------- K1: WH = relu(H @ W^T + b); also s, r; zero counters ----------------
__global__ __launch_bounds__(256) void k_gemm(
        const float* __restrict__ H, const float* __restrict__ W,
        const float* __restrict__ Wb,
        const float* __restrict__ vt, const float* __restrict__ vtb,
        const float* __restrict__ vr, const float* __restrict__ vrb,
        float* __restrict__ WH, float* __restrict__ s_out, float* __restrict__ r_out,
        int* __restrict__ rowcount, float* __restrict__ colsum, int* __restrict__ gcnt)
{
    __shared__ float hs[32 * 260];   // H tile [32][256] padded to 260
    __shared__ float wt[64 * 132];   // W^T chunk [64][128] padded to 132; reused as WH tile
    const int t = threadIdx.x;
    const int brow = blockIdx.x * 32;

    // zero counters for this call (consumed only by later kernels)
    {
        if (t < 32) {
            int idx = blockIdx.x * 32 + t;
            if (idx < N) rowcount[idx] = 0;
        }
        if (blockIdx.x == 0) {
            if (t < DOUT) colsum[t] = 0.f;
            if (t == 255) gcnt[0] = 0;
        }
    }

    // load H tile (zero-fill ghost rows)
    #pragma unroll
    for (int l = 0; l < 8; ++l) {
        int fid = t + l * 256;          // 0..2047 float4 slots
        int row = fid >> 6;             // 0..31
        int f4  = fid & 63;             // 0..63
        int grow = brow + row;
        float4 v = make_float4(0.f, 0.f, 0.f, 0.f);
        if (grow < N) v = *(const float4*)(H + (size_t)grow * DIN + f4 * 4);
        *(float4*)(hs + row * 260 + f4 * 4) = v;
    }

    float acc[4][4];
    #pragma unroll
    for (int i = 0; i < 4; ++i)
        #pragma unroll
        for (int j = 0; j < 4; ++j) acc[i][j] = 0.f;

    const int tx = t & 31;   // col group: cols tx*4..tx*4+3
    const int ty = t >> 5;   // row group: rows ty*4..ty*4+3

    for (int kc = 0; kc < 4; ++kc) {
        __syncthreads();
        // load W chunk transposed: wt[k][col] for k in [0,64)
        #pragma unroll
        for (int l = 0; l < 8; ++l) {
            int fid = t + l * 256;       // 0..2047
            int col = fid >> 4;          // 0..127
            int kq  = fid & 15;          // 0..15 (float4 within 64-chunk)
            float4 v = *(const float4*)(W + (size_t)col * DIN + kc * 64 + kq * 4);
            wt[(kq * 4 + 0) * 132 + col] = v.x;
            wt[(kq * 4 + 1) * 132 + col] = v.y;
            wt[(kq * 4 + 2) * 132 + col] = v.z;
            wt[(kq * 4 + 3) * 132 + col] = v.w;
        }
        __syncthreads();
        #pragma unroll 4
        for (int k = 0; k < 64; ++k) {
            float4 w4 = *(const float4*)(wt + k * 132 + tx * 4);
            int gk = kc * 64 + k;
            float h0 = hs[(ty * 4 + 0) * 260 + gk];
            float h1 = hs[(ty * 4 + 1) * 260 + gk];
            float h2 = hs[(ty * 4 + 2) * 260 + gk];
            float h3 = hs[(ty * 4 + 3) * 260 + gk];
            acc[0][0] += h0 * w4.x; acc[0][1] += h0 * w4.y; acc[0][2] += h0 * w4.z; acc[0][3] += h0 * w4.w;
            acc[1][0] += h1 * w4.x; acc[1][1] += h1 * w4.y; acc[1][2] += h1 * w4.z; acc[1][3] += h1 * w4.w;
            acc[2][0] += h2 * w4.x; acc[2][1] += h2 * w4.y; acc[2][2] += h2 * w4.z; acc[2][3] += h2 * w4.w;
            acc[3][0] += h3 * w4.x; acc[3][1] += h3 * w4.y; acc[3][2] += h3 * w4.z; acc[3][3] += h3 * w4.w;
        }
    }

    __syncthreads();   // done reading wt as W; reuse as WH tile [32][132]
    float4 bias = *(const float4*)(Wb + tx * 4);
    #pragma unroll
    for (int i = 0; i < 4; ++i) {
        int row = ty * 4 + i;
        int grow = brow + row;
        float4 o;
        o.x = fmaxf(acc[i][0] + bias.x, 0.f);
        o.y = fmaxf(acc[i][1] + bias.y, 0.f);
        o.z = fmaxf(acc[i][2] + bias.z, 0.f);
        o.w = fmaxf(acc[i][3] + bias.w, 0.f);
        *(float4*)(wt + row * 132 + tx * 4) = o;
        if (grow < N) *(float4*)(WH + (size_t)grow * DOUT + tx * 4) = o;
    }
    __syncthreads();

    // s, r: one wave per 8 rows; lane handles 2 cols
    const int wv = t >> 6, ln = t & 63;
    float vt0 = vt[2 * ln], vt1 = vt[2 * ln + 1];
    float vr0 = vr[2 * ln], vr1 = vr[2 * ln + 1];
    for (int rr = 0; rr < 8; ++rr) {
        int row = wv * 8 + rr;
        float a = wt[row * 132 + 2 * ln];
        float b = wt[row * 132 + 2 * ln + 1];
        float sp = a * vt0 + b * vt1;
        float rp = a * vr0 + b * vr1;
        #pragma unroll
        for (int off = 32; off; off >>= 1) {
            sp += __shfl_xor(sp, off);
            rp += __shfl_xor(rp, off);
        }
        int grow = brow + row;
        if (ln == 0 && grow < N) {
            s_out[grow] = sp + vtb[0];
            r_out[grow] = rp + vrb[0];
        }
    }
}

// ---------------- K2: pure-stream A -> compacted pair list (LDS-staged) ----------------
// Streaming loop touches only: global load, integer test, LDS atomic + LDS write.
// No vmcnt-draining dependent global atomics in the hot path.
__global__ __launch_bounds__(256) void k_scan(const float* __restrict__ A,
        const float* __restrict__ WH,
        unsigned* __restrict__ pairs, int* __restrict__ gcnt,
        float* __restrict__ colsum)
{
    __shared__ unsigned pbuf[LBUF];
    __shared__ int pcnt;
    __shared__ int gbase;
    if (threadIdx.x == 0) pcnt = 0;
    __syncthreads();

    // colsum duty on first 79 blocks (WH is 5 MB, L2/LLC resident)
    if (blockIdx.x < 79) {
        int col = threadIdx.x & 127;
        int rbase = blockIdx.x * 128 + (threadIdx.x >> 7);
        float cs = 0.f;
        #pragma unroll 4
        for (int k = 0; k < 64; ++k) {
            int row = rbase + 2 * k;
            if (row < N) cs += WH[(size_t)row * DOUT + col];
        }
        atomicAdd(&colsum[col], cs);
    }

    const uint4* Au = (const uint4*)A;
    const size_t stride = (size_t)gridDim.x * blockDim.x;
    const size_t total4 = (size_t)N * (size_t)N / 4;
    size_t i = (size_t)blockIdx.x * blockDim.x + threadIdx.x;

#define PUSH(E) do { \
        int pos_ = atomicAdd(&pcnt, 1); \
        if (pos_ < LBUF) pbuf[pos_] = (E); \
        else { int gp_ = atomicAdd(gcnt, 1); if (gp_ < MAXP) pairs[gp_] = (E); } \
    } while (0)

#define SCAN_BODY(I) do { \
        uint4 v_ = Au[I]; \
        if (v_.x | v_.y | v_.z | v_.w) { \
            unsigned eb_ = (unsigned)((I) * 4); \
            if (v_.x) PUSH(eb_); \
            if (v_.y) PUSH(eb_ + 1); \
            if (v_.z) PUSH(eb_ + 2); \
            if (v_.w) PUSH(eb_ + 3); \
        } } while (0)

    for (; i + stride < total4; i += 2 * stride) {
        SCAN_BODY(i);
        SCAN_BODY(i + stride);
    }
    for (; i < total4; i += stride) SCAN_BODY(i);
#undef SCAN_BODY
#undef PUSH

    // block flush: one global atomic per block, then coalesced copy
    __syncthreads();
    int cnt = pcnt; if (cnt > LBUF) cnt = LBUF;
    if (threadIdx.x == 0 && cnt > 0) gbase = atomicAdd(gcnt, cnt);
    __syncthreads();
    if (cnt > 0) {
        int base = gbase;
        for (int k = threadIdx.x; k < cnt; k += 256) {
            int gp = base + k;
            if (gp < MAXP) pairs[gp] = pbuf[k];
        }
    }
}

// ---------------- K2b: distribute pairs into per-row S/R buckets ----------------
__global__ __launch_bounds__(256) void k_build(const unsigned* __restrict__ pairs,
        const int* __restrict__ gcnt, int* __restrict__ rowcount,
        unsigned* __restrict__ rowdata)
{
    int npair = gcnt[0]; if (npair > MAXP) npair = MAXP;
    int tid = blockIdx.x * 256 + threadIdx.x;
    if (tid >= npair) return;
    unsigned e = pairs[tid];
    unsigned p = e / (unsigned)N;
    unsigned q = e - p * (unsigned)N;
    int pos = atomicAdd(&rowcount[p], 1);
    if (pos < CAP) rowdata[(size_t)p * CAP + pos] = q;               // S entry
    int pos2 = atomicAdd(&rowcount[q], 1);
    if (pos2 < CAP) rowdata[(size_t)q * CAP + pos2] = p | 0x8000u;   // R entry
}

// ---------------- K3: per-row merge + delta + gather ----------------
// out[i] = (C0*colsum + sum d*WH[col]) / (C0*N + sum d)
__global__ __launch_bounds__(256) void k_out(const float* __restrict__ WH,
        const float* __restrict__ s, const float* __restrict__ r,
        const float* __restrict__ colsum, const int* __restrict__ rowcount,
        const unsigned* __restrict__ rowdata, float* __restrict__ out)
{
    __shared__ unsigned ent[4][CAP];
    __shared__ float del[4][CAP];
    const int wv = threadIdx.x >> 6, ln = threadIdx.x & 63;
    const int row = blockIdx.x * 4 + wv;      // grid = 2500 exactly, no ghost rows
    int n = rowcount[row]; if (n > CAP) n = CAP;
    const float rrow = r[row];

    // load entries (lane-strided, <=3 slots each)
    unsigned my[3]; int myslot[3]; int nslots = 0;
    for (int slot = ln; slot < n; slot += 64) {
        unsigned e = rowdata[(size_t)row * CAP + slot];
        ent[wv][slot] = e;
        my[nslots] = e; myslot[nslots] = slot; nslots++;
    }
    __syncthreads();

    // merge: S-entry absorbs matching R-entry (same col); that R-entry dies.
    bool addr_[3] = {false, false, false}, dead[3] = {false, false, false};
    for (int j = 0; j < n; ++j) {
        unsigned bc = ent[wv][j];               // LDS broadcast
        #pragma unroll
        for (int k = 0; k < 3; ++k) {
            if (k < nslots && myslot[k] != j) {
                unsigned mine = my[k];
                if (((mine ^ bc) & 0x8000u) && ((mine & 0x3FFFu) == (bc & 0x3FFFu))) {
                    if (mine & 0x8000u) dead[k] = true;   // mine R, partner S exists
                    else addr_[k] = true;                  // mine S, absorb r[row]
                }
            }
        }
    }

    // delta per live entry; z partial
    float zpart = 0.f;
    #pragma unroll
    for (int k = 0; k < 3; ++k) {
        if (k < nslots) {
            float dlt = 0.f;
            if (!dead[k]) {
                unsigned col = my[k] & 0x3FFFu;
                float m = (my[k] & 0x8000u) ? rrow : s[col];
                if (addr_[k]) m += rrow;
                float sg = 1.f / (1.f + __expf(-m));
                dlt = expf(sg) - C0;
            }
            del[wv][myslot[k]] = dlt;
            zpart += dlt;
        }
    }
    #pragma unroll
    for (int off = 32; off; off >>= 1) zpart += __shfl_xor(zpart, off);
    __syncthreads();

    // gather: acc += d * WH[col][:]
    float acc0 = 0.f, acc1 = 0.f;
    for (int e2 = 0; e2 < n; ++e2) {
        float dlt = del[wv][e2];
        if (dlt != 0.f) {                        // wave-uniform skip of dead entries
            unsigned col = ent[wv][e2] & 0x3FFFu;
            float2 w2 = *(const float2*)(WH + (size_t)col * DOUT + 2 * ln);
            acc0 += dlt * w2.x;
            acc1 += dlt * w2.y;
        }
    }
    float inv = 1.f / (C0 * (float)N + zpart);
    int d = 2 * ln;
    out[(size_t)row * DOUT + d]     = (C0 * colsum[d]     + acc0) * inv;
    out[(size_t)row * DOUT + d + 1] = (C0 * colsum[d + 1] + acc1) * inv;
}

extern "C" void kernel_launch(void* const* d_in, const int* in_sizes, int n_in,
                              void* d_out, int out_size, void* d_ws, size_t ws_size,
                              hipStream_t stream)
{
    (void)in_sizes; (void)n_in; (void)out_size; (void)ws_size;
    const float* H   = (const float*)d_in[0];
    const float* A   = (const float*)d_in[1];
    const float* W   = (const float*)d_in[2];
    const float* Wb  = (const float*)d_in[3];
    const float* vt  = (const float*)d_in[4];
    const float* vtb = (const float*)d_in[5];
    const float* vr  = (const float*)d_in[6];
    const float* vrb = (const float*)d_in[7];

    char* ws = (char*)d_ws;
    size_t off = 0;
    float* WH = (float*)(ws + off);        off += (size_t)N * DOUT * 4;     // 5.12 MB
    float* s_ = (float*)(ws + off);        off += 40960;
    float* r_ = (float*)(ws + off);        off += 40960;
    float* colsum = (float*)(ws + off);    off += 1024;
    int* rowcount = (int*)(ws + off);      off += 40960;
    int* gcnt = (int*)(ws + off);          off += 256;
    unsigned* pairs = (unsigned*)(ws + off); off += (size_t)MAXP * 4;       // 1.6 MB
    unsigned* rowdata = (unsigned*)(ws + off);                              // 7.68 MB

    k_gemm<<<(N + 31) / 32, 256, 0, stream>>>(H, W, Wb, vt, vtb, vr, vrb,
                                              WH, s_, r_, rowcount, colsum, gcnt);
    k_scan<<<2048, 256, 0, stream>>>(A, WH, pairs, gcnt, colsum);
    k_build<<<(MAXP + 255) / 256, 256, 0, stream>>>(pairs, gcnt, rowcount, rowdata);
    k_out<<<N / 4, 256, 0, stream>>>(WH, s_, r_, colsum, rowcount, rowdata, (float*)d_out);
}

// Round 5
// 269.282 us; speedup vs baseline: 1.1156x; 1.1156x over previous
//
#include <hip/hip_runtime.h>
#include <math.h>

#define N 10000
#define DIN 256
#define DOUT 128
#define CAP 192
#define LBUF 1024
#define NGB 313                  // gemm grid blocks = ceil(N/32)
#define C0 1.6487212707001282f   // exp(sigmoid(0)) = exp(0.5)

typedef unsigned int u32x4 __attribute__((ext_vector_type(4)));

// ---------------- K1: WH = relu(H @ W^T + b); s, r; colsum PARTIALS; zero rowcount ----------------
__global__ __launch_bounds__(256) void k_gemm(
        const float* __restrict__ H, const float* __restrict__ W,
        const float* __restrict__ Wb,
        const float* __restrict__ vt, const float* __restrict__ vtb,
        const float* __restrict__ vr, const float* __restrict__ vrb,
        float* __restrict__ WH, float* __restrict__ s_out, float* __restrict__ r_out,
        int* __restrict__ rowcount, float* __restrict__ cspart)
{
    __shared__ float hs[32 * 260];   // H tile [32][256] padded to 260
    __shared__ float wt[64 * 132];   // W^T chunk [64][128] padded to 132; reused as WH tile
    const int t = threadIdx.x;
    const int brow = blockIdx.x * 32;

    // zero rowcount (written here, atomically consumed only in K2 -> cross-dispatch safe)
    if (t < 32) {
        int idx = brow + t;
        if (idx < N) rowcount[idx] = 0;
    }

    // load H tile (zero-fill ghost rows)
    #pragma unroll
    for (int l = 0; l < 8; ++l) {
        int fid = t + l * 256;          // 0..2047 float4 slots
        int row = fid >> 6;             // 0..31
        int f4  = fid & 63;             // 0..63
        int grow = brow + row;
        float4 v = make_float4(0.f, 0.f, 0.f, 0.f);
        if (grow < N) v = *(const float4*)(H + (size_t)grow * DIN + f4 * 4);
        *(float4*)(hs + row * 260 + f4 * 4) = v;
    }

    float acc[4][4];
    #pragma unroll
    for (int i = 0; i < 4; ++i)
        #pragma unroll
        for (int j = 0; j < 4; ++j) acc[i][j] = 0.f;

    const int tx = t & 31;   // col group: cols tx*4..tx*4+3
    const int ty = t >> 5;   // row group: rows ty*4..ty*4+3

    for (int kc = 0; kc < 4; ++kc) {
        __syncthreads();
        // load W chunk transposed: wt[k][col] for k in [0,64)
        #pragma unroll
        for (int l = 0; l < 8; ++l) {
            int fid = t + l * 256;       // 0..2047
            int col = fid >> 4;          // 0..127
            int kq  = fid & 15;          // 0..15 (float4 within 64-chunk)
            float4 v = *(const float4*)(W + (size_t)col * DIN + kc * 64 + kq * 4);
            wt[(kq * 4 + 0) * 132 + col] = v.x;
            wt[(kq * 4 + 1) * 132 + col] = v.y;
            wt[(kq * 4 + 2) * 132 + col] = v.z;
            wt[(kq * 4 + 3) * 132 + col] = v.w;
        }
        __syncthreads();
        #pragma unroll 4
        for (int k = 0; k < 64; ++k) {
            float4 w4 = *(const float4*)(wt + k * 132 + tx * 4);
            int gk = kc * 64 + k;
            float h0 = hs[(ty * 4 + 0) * 260 + gk];
            float h1 = hs[(ty * 4 + 1) * 260 + gk];
            float h2 = hs[(ty * 4 + 2) * 260 + gk];
            float h3 = hs[(ty * 4 + 3) * 260 + gk];
            acc[0][0] += h0 * w4.x; acc[0][1] += h0 * w4.y; acc[0][2] += h0 * w4.z; acc[0][3] += h0 * w4.w;
            acc[1][0] += h1 * w4.x; acc[1][1] += h1 * w4.y; acc[1][2] += h1 * w4.z; acc[1][3] += h1 * w4.w;
            acc[2][0] += h2 * w4.x; acc[2][1] += h2 * w4.y; acc[2][2] += h2 * w4.z; acc[2][3] += h2 * w4.w;
            acc[3][0] += h3 * w4.x; acc[3][1] += h3 * w4.y; acc[3][2] += h3 * w4.z; acc[3][3] += h3 * w4.w;
        }
    }

    __syncthreads();   // done reading wt as W; reuse as WH tile [32][132]
    float4 bias = *(const float4*)(Wb + tx * 4);
    #pragma unroll
    for (int i = 0; i < 4; ++i) {
        int row = ty * 4 + i;
        int grow = brow + row;
        float4 o;
        o.x = fmaxf(acc[i][0] + bias.x, 0.f);
        o.y = fmaxf(acc[i][1] + bias.y, 0.f);
        o.z = fmaxf(acc[i][2] + bias.z, 0.f);
        o.w = fmaxf(acc[i][3] + bias.w, 0.f);
        *(float4*)(wt + row * 132 + tx * 4) = o;
        if (grow < N) *(float4*)(WH + (size_t)grow * DOUT + tx * 4) = o;
    }
    __syncthreads();

    // s, r: one wave per 8 rows; lane handles 2 cols
    const int wv = t >> 6, ln = t & 63;
    float vt0 = vt[2 * ln], vt1 = vt[2 * ln + 1];
    float vr0 = vr[2 * ln], vr1 = vr[2 * ln + 1];
    for (int rr = 0; rr < 8; ++rr) {
        int row = wv * 8 + rr;
        float a = wt[row * 132 + 2 * ln];
        float b = wt[row * 132 + 2 * ln + 1];
        float sp = a * vt0 + b * vt1;
        float rp = a * vr0 + b * vr1;
        #pragma unroll
        for (int off = 32; off; off >>= 1) {
            sp += __shfl_xor(sp, off);
            rp += __shfl_xor(rp, off);
        }
        int grow = brow + row;
        if (ln == 0 && grow < N) {
            s_out[grow] = sp + vtb[0];
            r_out[grow] = rp + vrb[0];
        }
    }

    // colsum PARTIAL: plain unconditional store, no zeroing/atomics needed.
    if (t < 128) {
        float cs = 0.f;
        int nvalid = N - brow; if (nvalid > 32) nvalid = 32;
        for (int rr = 0; rr < nvalid; ++rr) cs += wt[rr * 132 + t];
        cspart[(size_t)blockIdx.x * 128 + t] = cs;
    }
}

// ---------------- K2: nt-stream A -> LDS buffer -> flush into per-row buckets ----------------
// Hot loop: 4x-unrolled nontemporal uint4 loads (bypass L2, keep WH resident),
// integer test, rare {LDS atomic + LDS store}. Bucket scatter once per block at end.
// Block 0 additionally reduces colsum partials (plain stores; consumed in K3).
__global__ __launch_bounds__(256) void k_scan(const float* __restrict__ A,
        const float* __restrict__ cspart, float* __restrict__ colsum,
        int* __restrict__ rowcount, unsigned* __restrict__ rowdata)
{
    __shared__ unsigned pbuf[LBUF];
    __shared__ int pcnt;
    if (threadIdx.x == 0) pcnt = 0;
    __syncthreads();

    if (blockIdx.x == 0 && threadIdx.x < 128) {
        float cs = 0.f;
        for (int b = 0; b < NGB; ++b) cs += cspart[(size_t)b * 128 + threadIdx.x];
        colsum[threadIdx.x] = cs;
    }

    const u32x4* Au = (const u32x4*)A;
    const size_t s1 = (size_t)gridDim.x * blockDim.x;
    const size_t total4 = (size_t)N * (size_t)N / 4;
    size_t i = (size_t)blockIdx.x * blockDim.x + threadIdx.x;

#define PUSH(E) do { \
        int pos_ = atomicAdd(&pcnt, 1); \
        if (pos_ < LBUF) pbuf[pos_] = (E); \
        else { /* overflow: direct bucket emit (statistically never) */ \
            unsigned p_ = (E) / (unsigned)N, q_ = (E) - p_ * (unsigned)N; \
            int a_ = atomicAdd(&rowcount[p_], 1); \
            if (a_ < CAP) rowdata[(size_t)p_ * CAP + a_] = q_; \
            int b_ = atomicAdd(&rowcount[q_], 1); \
            if (b_ < CAP) rowdata[(size_t)q_ * CAP + b_] = p_ | 0x8000u; \
        } \
    } while (0)

#define BODY(V, I) do { \
        if ((V).x | (V).y | (V).z | (V).w) { \
            unsigned eb_ = (unsigned)((I) * 4); \
            if ((V).x) PUSH(eb_); \
            if ((V).y) PUSH(eb_ + 1); \
            if ((V).z) PUSH(eb_ + 2); \
            if ((V).w) PUSH(eb_ + 3); \
        } } while (0)

    for (; i + 3 * s1 < total4; i += 4 * s1) {
        u32x4 v0 = __builtin_nontemporal_load(Au + i);
        u32x4 v1 = __builtin_nontemporal_load(Au + i + s1);
        u32x4 v2 = __builtin_nontemporal_load(Au + i + 2 * s1);
        u32x4 v3 = __builtin_nontemporal_load(Au + i + 3 * s1);
        BODY(v0, i);
        BODY(v1, i + s1);
        BODY(v2, i + 2 * s1);
        BODY(v3, i + 3 * s1);
    }
    for (; i < total4; i += s1) {
        u32x4 v = __builtin_nontemporal_load(Au + i);
        BODY(v, i);
    }
#undef BODY
#undef PUSH

    // flush: distribute this block's entries into per-row S/R buckets
    __syncthreads();
    int cnt = pcnt; if (cnt > LBUF) cnt = LBUF;
    for (int k = threadIdx.x; k < cnt; k += 256) {
        unsigned e = pbuf[k];
        unsigned p = e / (unsigned)N;
        unsigned q = e - p * (unsigned)N;
        int pos = atomicAdd(&rowcount[p], 1);
        if (pos < CAP) rowdata[(size_t)p * CAP + pos] = q;               // S entry
        int pos2 = atomicAdd(&rowcount[q], 1);
        if (pos2 < CAP) rowdata[(size_t)q * CAP + pos2] = p | 0x8000u;   // R entry
    }
}

// ---------------- K3: per-row merge + delta + gather ----------------
// out[i] = (C0*colsum + sum d*WH[col]) / (C0*N + sum d)
__global__ __launch_bounds__(256) void k_out(const float* __restrict__ WH,
        const float* __restrict__ s, const float* __restrict__ r,
        const float* __restrict__ colsum, const int* __restrict__ rowcount,
        const unsigned* __restrict__ rowdata, float* __restrict__ out)
{
    __shared__ unsigned ent[4][CAP];
    __shared__ float del[4][CAP];
    const int wv = threadIdx.x >> 6, ln = threadIdx.x & 63;
    const int row = blockIdx.x * 4 + wv;      // grid = 2500 exactly, no ghost rows
    int n = rowcount[row]; if (n > CAP) n = CAP;
    const float rrow = r[row];

    // load entries (lane-strided, <=3 slots each)
    unsigned my[3]; int myslot[3]; int nslots = 0;
    for (int slot = ln; slot < n; slot += 64) {
        unsigned e = rowdata[(size_t)row * CAP + slot];
        ent[wv][slot] = e;
        my[nslots] = e; myslot[nslots] = slot; nslots++;
    }
    __syncthreads();

    // merge: S-entry absorbs matching R-entry (same col); that R-entry dies.
    bool addr_[3] = {false, false, false}, dead[3] = {false, false, false};
    for (int j = 0; j < n; ++j) {
        unsigned bc = ent[wv][j];               // LDS broadcast
        #pragma unroll
        for (int k = 0; k < 3; ++k) {
            if (k < nslots && myslot[k] != j) {
                unsigned mine = my[k];
                if (((mine ^ bc) & 0x8000u) && ((mine & 0x3FFFu) == (bc & 0x3FFFu))) {
                    if (mine & 0x8000u) dead[k] = true;   // mine R, partner S exists
                    else addr_[k] = true;                  // mine S, absorb r[row]
                }
            }
        }
    }

    // delta per live entry; z partial
    float zpart = 0.f;
    #pragma unroll
    for (int k = 0; k < 3; ++k) {
        if (k < nslots) {
            float dlt = 0.f;
            if (!dead[k]) {
                unsigned col = my[k] & 0x3FFFu;
                float m = (my[k] & 0x8000u) ? rrow : s[col];
                if (addr_[k]) m += rrow;
                float sg = 1.f / (1.f + __expf(-m));
                dlt = expf(sg) - C0;
            }
            del[wv][myslot[k]] = dlt;
            zpart += dlt;
        }
    }
    #pragma unroll
    for (int off = 32; off; off >>= 1) zpart += __shfl_xor(zpart, off);
    __syncthreads();

    // gather: acc += d * WH[col][:]
    float acc0 = 0.f, acc1 = 0.f;
    for (int e2 = 0; e2 < n; ++e2) {
        float dlt = del[wv][e2];
        if (dlt != 0.f) {                        // wave-uniform skip of dead entries
            unsigned col = ent[wv][e2] & 0x3FFFu;
            float2 w2 = *(const float2*)(WH + (size_t)col * DOUT + 2 * ln);
            acc0 += dlt * w2.x;
            acc1 += dlt * w2.y;
        }
    }
    float inv = 1.f / (C0 * (float)N + zpart);
    int d = 2 * ln;
    out[(size_t)row * DOUT + d]     = (C0 * colsum[d]     + acc0) * inv;
    out[(size_t)row * DOUT + d + 1] = (C0 * colsum[d + 1] + acc1) * inv;
}

extern "C" void kernel_launch(void* const* d_in, const int* in_sizes, int n_in,
                              void* d_out, int out_size, void* d_ws, size_t ws_size,
                              hipStream_t stream)
{
    (void)in_sizes; (void)n_in; (void)out_size; (void)ws_size;
    const float* H   = (const float*)d_in[0];
    const float* A   = (const float*)d_in[1];
    const float* W   = (const float*)d_in[2];
    const float* Wb  = (const float*)d_in[3];
    const float* vt  = (const float*)d_in[4];
    const float* vtb = (const float*)d_in[5];
    const float* vr  = (const float*)d_in[6];
    const float* vrb = (const float*)d_in[7];

    char* ws = (char*)d_ws;
    size_t off = 0;
    float* WH = (float*)(ws + off);        off += (size_t)N * DOUT * 4;     // 5.12 MB
    float* s_ = (float*)(ws + off);        off += 40960;
    float* r_ = (float*)(ws + off);        off += 40960;
    float* colsum = (float*)(ws + off);    off += 1024;
    float* cspart = (float*)(ws + off);    off += (size_t)NGB * 128 * 4;    // 160 KB
    int* rowcount = (int*)(ws + off);      off += 40960;
    unsigned* rowdata = (unsigned*)(ws + off);                              // 7.68 MB

    k_gemm<<<NGB, 256, 0, stream>>>(H, W, Wb, vt, vtb, vr, vrb,
                                    WH, s_, r_, rowcount, cspart);
    k_scan<<<2048, 256, 0, stream>>>(A, cspart, colsum, rowcount, rowdata);
    k_out<<<N / 4, 256, 0, stream>>>(WH, s_, r_, colsum, rowcount, rowdata, (float*)d_out);
}